// Round 1
// baseline (516.374 us; speedup 1.0000x reference)
//
#include <hip/hip_runtime.h>
#include <math.h>

#define NROWS 8192
#define NCLS  5994
#define KDIM  192
#define SSC   30.0f
#define COSM  0.9800665778412416f
#define SINM  0.19866933079506122f
#define THRV  (-0.9800665778412416f)
#define MMV   0.03973386615901225f

#define TC     32     // classes per LDS tile
#define CPB    1499   // classes per class-group block (ceil(5994/4))
#define NTILES 47     // ceil(1499/32)

typedef const __attribute__((address_space(1))) unsigned int* gp32_t;
typedef __attribute__((address_space(3))) unsigned int* lp32_t;

__device__ __forceinline__ void gload16(const void* g, void* l) {
  __builtin_amdgcn_global_load_lds((gp32_t)g, (lp32_t)l, 16, 0, 0);
}

// ---------------- W row L2-normalize ----------------
__global__ __launch_bounds__(64) void wnorm_kernel(const float* __restrict__ W,
                                                   float* __restrict__ Wn) {
  const int row = blockIdx.x;
  const int lane = threadIdx.x;
  const float* w = W + (size_t)row * KDIM;
  float a = w[lane], b = w[lane + 64], c = w[lane + 128];
  float ss = a * a + b * b + c * c;
  #pragma unroll
  for (int m = 1; m < 64; m <<= 1) ss += __shfl_xor(ss, m);
  const float rn = 1.0f / fmaxf(sqrtf(ss), 1e-12f);
  float* o = Wn + (size_t)row * KDIM;
  o[lane] = a * rn;
  o[lane + 64] = b * rn;
  o[lane + 128] = c * rn;
}

// ---------------- main fused cosine + partial softmax stats ----------------
// grid: (64 rowgroups, 4 classgroups), block 512 (8 waves).
// wave handles 16 rows; lane=(rg,kc): 2 rows x 24-float k-slice in registers.
__global__ __launch_bounds__(512, 1) void arc_main(
    const float* __restrict__ x, const float* __restrict__ Wn,
    float* __restrict__ s_part, float* __restrict__ best_part,
    int* __restrict__ besti_part) {
  __shared__ float wt[2][TC * KDIM];
  const int tid = threadIdx.x;
  const int wave = tid >> 6, lane = tid & 63;
  const int rg = lane & 7, kc = lane >> 3;
  const int r0 = blockIdx.x * 128 + wave * 16 + rg * 2;
  const int cg = blockIdx.y;
  const int cmin = cg * CPB;
  const int cmax = min(NCLS, cmin + CPB);

  // load + in-register normalize the two x row slices
  float xr0[24], xr1[24];
  {
    const float4* p0 = (const float4*)(x + (size_t)r0 * KDIM + kc * 24);
    const float4* p1 = (const float4*)(x + (size_t)(r0 + 1) * KDIM + kc * 24);
    #pragma unroll
    for (int j = 0; j < 6; ++j) {
      float4 v = p0[j];
      xr0[4 * j] = v.x; xr0[4 * j + 1] = v.y; xr0[4 * j + 2] = v.z; xr0[4 * j + 3] = v.w;
      float4 u = p1[j];
      xr1[4 * j] = u.x; xr1[4 * j + 1] = u.y; xr1[4 * j + 2] = u.z; xr1[4 * j + 3] = u.w;
    }
  }
  float ss0 = 0.f, ss1 = 0.f;
  #pragma unroll
  for (int i = 0; i < 24; ++i) {
    ss0 = fmaf(xr0[i], xr0[i], ss0);
    ss1 = fmaf(xr1[i], xr1[i], ss1);
  }
  #pragma unroll
  for (int m = 8; m < 64; m <<= 1) { ss0 += __shfl_xor(ss0, m); ss1 += __shfl_xor(ss1, m); }
  const float rn0 = 1.0f / fmaxf(sqrtf(ss0), 1e-12f);
  const float rn1 = 1.0f / fmaxf(sqrtf(ss1), 1e-12f);
  #pragma unroll
  for (int i = 0; i < 24; ++i) { xr0[i] *= rn0; xr1[i] *= rn1; }

  float s0 = 0.f, s1 = 0.f, best0 = -2.f, best1 = -2.f;
  int bi0 = 0, bi1 = 0;

  // stage tile 0 (linear copy, 24KB, 512 threads x 48B)
  {
    const char* g = (const char*)(Wn + (size_t)cmin * KDIM);
    char* l = (char*)&wt[0][0];
    #pragma unroll
    for (int j = 0; j < 3; ++j) {
      const int off = j * 8192 + tid * 16;
      gload16(g + off, l + off);
    }
  }
  asm volatile("s_waitcnt vmcnt(0)" ::: "memory");
  __syncthreads();

  for (int t = 0; t < NTILES; ++t) {
    const int cur = t & 1;
    if (t + 1 < NTILES) {  // prefetch next tile into other buffer
      const char* g = (const char*)(Wn + (size_t)(cmin + (t + 1) * TC) * KDIM);
      char* l = (char*)&wt[cur ^ 1][0];
      #pragma unroll
      for (int j = 0; j < 3; ++j) {
        const int off = j * 8192 + tid * 16;
        gload16(g + off, l + off);
      }
    }
    const int c0 = cmin + t * TC;
    #pragma unroll 8
    for (int c = 0; c < TC; ++c) {
      const float4* wrow = (const float4*)&wt[cur][c * KDIM + kc * 24];
      float p0 = 0.f, p1 = 0.f;
      #pragma unroll
      for (int j = 0; j < 6; ++j) {
        float4 wv = wrow[j];
        p0 = fmaf(xr0[4 * j + 0], wv.x, p0);
        p1 = fmaf(xr1[4 * j + 0], wv.x, p1);
        p0 = fmaf(xr0[4 * j + 1], wv.y, p0);
        p1 = fmaf(xr1[4 * j + 1], wv.y, p1);
        p0 = fmaf(xr0[4 * j + 2], wv.z, p0);
        p1 = fmaf(xr1[4 * j + 2], wv.z, p1);
        p0 = fmaf(xr0[4 * j + 3], wv.w, p0);
        p1 = fmaf(xr1[4 * j + 3], wv.w, p1);
      }
      // reduce partial dots across the 8 kc lanes (masks 8,16,32)
      #pragma unroll
      for (int m = 8; m < 64; m <<= 1) { p0 += __shfl_xor(p0, m); p1 += __shfl_xor(p1, m); }
      const int gc = c0 + c;
      if (gc < cmax) {  // uniform branch; masks OOB-pad garbage
        s0 += __expf(fmaf(SSC, p0, -SSC));
        s1 += __expf(fmaf(SSC, p1, -SSC));
        if (p0 > best0) { best0 = p0; bi0 = gc; }
        if (p1 > best1) { best1 = p1; bi1 = gc; }
      }
    }
    asm volatile("s_waitcnt vmcnt(0)" ::: "memory");
    __syncthreads();
  }

  if (kc == 0) {  // all kc lanes hold identical stats; one writes
    s_part[(size_t)r0 * 4 + cg] = s0;
    best_part[(size_t)r0 * 4 + cg] = best0;
    besti_part[(size_t)r0 * 4 + cg] = bi0;
    s_part[(size_t)(r0 + 1) * 4 + cg] = s1;
    best_part[(size_t)(r0 + 1) * 4 + cg] = best1;
    besti_part[(size_t)(r0 + 1) * 4 + cg] = bi1;
  }
}

// ---------------- per-row merge: label logit patch + loss ----------------
__global__ __launch_bounds__(256) void arc_merge(
    const float* __restrict__ x, const float* __restrict__ Wn,
    const int* __restrict__ labels, const float* __restrict__ s_part,
    const float* __restrict__ best_part, const int* __restrict__ besti_part,
    float* __restrict__ loss_row, float* __restrict__ corr_row) {
  const int r = blockIdx.x * 4 + (threadIdx.x >> 6);
  const int lane = threadIdx.x & 63;
  const float* xr = x + (size_t)r * KDIM;
  const float a = xr[lane], b = xr[lane + 64], c = xr[lane + 128];
  float ss = a * a + b * b + c * c;
  #pragma unroll
  for (int m = 1; m < 64; m <<= 1) ss += __shfl_xor(ss, m);
  const int y = labels[r];
  const float* wy = Wn + (size_t)y * KDIM;
  float dot = a * wy[lane] + b * wy[lane + 64] + c * wy[lane + 128];
  #pragma unroll
  for (int m = 1; m < 64; m <<= 1) dot += __shfl_xor(dot, m);
  if (lane == 0) {
    const float rn = 1.0f / fmaxf(sqrtf(ss), 1e-12f);
    const float cy = dot * rn;
    float s = 0.f, best = -3.f;
    int bi = -1;
    #pragma unroll
    for (int g = 0; g < 4; ++g) {
      s += s_part[(size_t)r * 4 + g];
      const float bp = best_part[(size_t)r * 4 + g];
      if (bp > best) { best = bp; bi = besti_part[(size_t)r * 4 + g]; }
    }
    const float sine = sqrtf(fmaxf(0.f, 1.f - cy * cy));
    const float cp = (cy > THRV) ? (cy * COSM - sine * SINM) : (cy - MMV);
    const float zy = SSC * cp;
    const float zy0 = SSC * cy;
    const float s2 = s - __expf(zy0 - SSC) + __expf(zy - SSC);
    loss_row[r] = SSC + logf(s2) - zy;
    corr_row[r] = (bi == y) ? 1.f : 0.f;
  }
}

// ---------------- final reduction ----------------
__global__ __launch_bounds__(256) void arc_final(const float* __restrict__ loss_row,
                                                 const float* __restrict__ corr_row,
                                                 float* __restrict__ out) {
  __shared__ double redl[256];
  __shared__ double redc[256];
  const int t = threadIdx.x;
  double ls = 0.0, cs = 0.0;
  for (int i = t; i < NROWS; i += 256) {
    ls += (double)loss_row[i];
    cs += (double)corr_row[i];
  }
  redl[t] = ls; redc[t] = cs;
  __syncthreads();
  for (int st = 128; st > 0; st >>= 1) {
    if (t < st) { redl[t] += redl[t + st]; redc[t] += redc[t + st]; }
    __syncthreads();
  }
  if (t == 0) {
    out[0] = (float)(redl[0] / (double)NROWS);
    out[1] = (float)redc[0];
  }
}

extern "C" void kernel_launch(void* const* d_in, const int* in_sizes, int n_in,
                              void* d_out, int out_size, void* d_ws, size_t ws_size,
                              hipStream_t stream) {
  const float* x = (const float*)d_in[0];
  const int* labels = (const int*)d_in[1];
  const float* W = (const float*)d_in[2];
  float* out = (float*)d_out;
  char* ws = (char*)d_ws;

  // ws layout (Wn padded to 6016 rows so unguarded tile staging stays in ws)
  float* Wn = (float*)ws;                       // 6016*192*4 = 4,620,288 B
  size_t off = (size_t)6016 * KDIM * 4;
  float* s_part = (float*)(ws + off);    off += (size_t)NROWS * 4 * 4;
  float* best_part = (float*)(ws + off); off += (size_t)NROWS * 4 * 4;
  int* besti_part = (int*)(ws + off);    off += (size_t)NROWS * 4 * 4;
  float* loss_row = (float*)(ws + off);  off += (size_t)NROWS * 4;
  float* corr_row = (float*)(ws + off);  off += (size_t)NROWS * 4;

  hipLaunchKernelGGL(wnorm_kernel, dim3(NCLS), dim3(64), 0, stream, W, Wn);
  hipLaunchKernelGGL(arc_main, dim3(64, 4), dim3(512), 0, stream, x, Wn,
                     s_part, best_part, besti_part);
  hipLaunchKernelGGL(arc_merge, dim3(NROWS / 4), dim3(256), 0, stream, x, Wn,
                     labels, s_part, best_part, besti_part, loss_row, corr_row);
  hipLaunchKernelGGL(arc_final, dim3(1), dim3(256), 0, stream, loss_row,
                     corr_row, out);
}

// Round 2
// 122.794 us; speedup vs baseline: 4.2052x; 4.2052x over previous
//
#include <hip/hip_runtime.h>
#include <math.h>

#define NROWS 8192
#define NCLS  5994
#define NCLSP 6016
#define KDIM  192
#define PITCHB 384
#define SSC   30.0f
#define COSM  0.9800665778412416f
#define SINM  0.19866933079506122f
#define THRV  (-0.9800665778412416f)
#define MMV   0.03973386615901225f
#define NCG   8
#define CPG   752
#define NT    47
#define FLAG_GAP 2.0e-4f

typedef float f32x4 __attribute__((ext_vector_type(4)));
typedef short bf16x8 __attribute__((ext_vector_type(8)));

typedef const __attribute__((address_space(1))) unsigned int* gp32_t;
typedef __attribute__((address_space(3))) unsigned int* lp32_t;
__device__ __forceinline__ void gload16(const void* g, void* l) {
  __builtin_amdgcn_global_load_lds((gp32_t)g, (lp32_t)l, 16, 0, 0);
}

__device__ __forceinline__ unsigned short f2bf_rne(float f) {
  unsigned int u = __float_as_uint(f);
  u = u + 0x7fffu + ((u >> 16) & 1u);
  return (unsigned short)(u >> 16);
}
__device__ __forceinline__ float bf2f(unsigned short h) {
  return __uint_as_float(((unsigned int)h) << 16);
}

// ---------- W prep: L2-normalize, split to bf16 hi/lo, store 1/||w|| ----------
__global__ __launch_bounds__(256) void wprep(const float* __restrict__ W,
                                             unsigned short* __restrict__ Whi,
                                             unsigned short* __restrict__ Wlo,
                                             float* __restrict__ rnw) {
  const int r = blockIdx.x * 4 + (threadIdx.x >> 6);
  const int lane = threadIdx.x & 63;
  if (r >= NCLS) {  // zero-pad rows [5994,6016)
    if (r < NCLSP) {
      #pragma unroll
      for (int j = 0; j < 3; ++j) { Whi[(size_t)r*KDIM + lane + j*64] = 0; Wlo[(size_t)r*KDIM + lane + j*64] = 0; }
      if (lane == 0) rnw[r] = 0.f;
    }
    return;
  }
  const float* w = W + (size_t)r * KDIM;
  float e0 = w[lane], e1 = w[lane+64], e2 = w[lane+128];
  float ss = e0*e0 + e1*e1 + e2*e2;
  #pragma unroll
  for (int m = 1; m < 64; m <<= 1) ss += __shfl_xor(ss, m);
  const float rn = 1.0f / fmaxf(sqrtf(ss), 1e-12f);
  float ev[3] = {e0, e1, e2};
  #pragma unroll
  for (int j = 0; j < 3; ++j) {
    float xn = ev[j] * rn;
    unsigned short hi = f2bf_rne(xn);
    float lo = xn - bf2f(hi);
    Whi[(size_t)r*KDIM + lane + j*64] = hi;
    Wlo[(size_t)r*KDIM + lane + j*64] = f2bf_rne(lo);
  }
  if (lane == 0) rnw[r] = rn;
}

// ---------- x prep: L2-normalize, split to bf16 hi/lo; zero flag counter ----------
__global__ __launch_bounds__(256) void xprep(const float* __restrict__ x,
                                             unsigned short* __restrict__ Xhi,
                                             unsigned short* __restrict__ Xlo,
                                             int* __restrict__ nflag) {
  if (blockIdx.x == 0 && threadIdx.x == 0) *nflag = 0;
  const int r = blockIdx.x * 4 + (threadIdx.x >> 6);
  const int lane = threadIdx.x & 63;
  const float* xr = x + (size_t)r * KDIM;
  float e0 = xr[lane], e1 = xr[lane+64], e2 = xr[lane+128];
  float ss = e0*e0 + e1*e1 + e2*e2;
  #pragma unroll
  for (int m = 1; m < 64; m <<= 1) ss += __shfl_xor(ss, m);
  const float rn = 1.0f / fmaxf(sqrtf(ss), 1e-12f);
  float ev[3] = {e0, e1, e2};
  #pragma unroll
  for (int j = 0; j < 3; ++j) {
    float xn = ev[j] * rn;
    unsigned short hi = f2bf_rne(xn);
    float lo = xn - bf2f(hi);
    Xhi[(size_t)r*KDIM + lane + j*64] = hi;
    Xlo[(size_t)r*KDIM + lane + j*64] = f2bf_rne(lo);
  }
}

// ---------- main: split-3 bf16 MFMA cosine + fused exp-sum + top-2 ----------
__global__ __launch_bounds__(256, 2) void arc_main(
    const unsigned short* __restrict__ Xhi, const unsigned short* __restrict__ Xlo,
    const unsigned short* __restrict__ Whi, const unsigned short* __restrict__ Wlo,
    float* __restrict__ s_part, float* __restrict__ b1p,
    float* __restrict__ b2p, float* __restrict__ bip) {
  __shared__ __align__(16) char lds[2][12288];
  const int tid = threadIdx.x;
  const int wave = tid >> 6, lane = tid & 63;
  const int col = lane & 15, kb = lane >> 4;
  const int swz = (col & 7) << 4;
  const int r0w = (blockIdx.x * 4 + wave) * 32;
  const int c0g = blockIdx.y * CPG;

  // A fragments (32 rows x 192 k, hi+lo) resident in registers
  bf16x8 ahi[2][6], alo[2][6];
  #pragma unroll
  for (int mf = 0; mf < 2; ++mf)
    #pragma unroll
    for (int ks = 0; ks < 6; ++ks) {
      size_t off = (size_t)(r0w + mf*16 + col) * KDIM + ks*32 + kb*8;
      ahi[mf][ks] = *(const bf16x8*)(Xhi + off);
      alo[mf][ks] = *(const bf16x8*)(Xlo + off);
    }

  // staging map: linear LDS dest, inverse-swizzled global source
  int sarr[3], soff[3];
  #pragma unroll
  for (int j = 0; j < 3; ++j) {
    int q = tid + j*256;
    int arr = q / 384, rem = q % 384;
    int rr = rem / 24, cc = rem % 24;
    sarr[j] = arr;
    soff[j] = rr * PITCHB + ((cc*16) ^ ((rr & 7) << 4));
  }

  {
    const char* bh = (const char*)(Whi + (size_t)c0g * KDIM);
    const char* bl = (const char*)(Wlo + (size_t)c0g * KDIM);
    #pragma unroll
    for (int j = 0; j < 3; ++j)
      gload16((sarr[j] ? bl : bh) + soff[j], &lds[0][j*4096 + tid*16]);
  }
  __syncthreads();

  float sacc[8], v1[8], v2[8], i1[8];
  #pragma unroll
  for (int s = 0; s < 8; ++s) { sacc[s] = 0.f; v1[s] = -2.f; v2[s] = -2.f; i1[s] = 0.f; }
  const f32x4 z4 = {0.f, 0.f, 0.f, 0.f};

  for (int t = 0; t < NT; ++t) {
    const int cur = t & 1;
    if (t + 1 < NT) {
      const char* bh = (const char*)(Whi + (size_t)(c0g + (t+1)*16) * KDIM);
      const char* bl = (const char*)(Wlo + (size_t)(c0g + (t+1)*16) * KDIM);
      #pragma unroll
      for (int j = 0; j < 3; ++j)
        gload16((sarr[j] ? bl : bh) + soff[j], &lds[cur^1][j*4096 + tid*16]);
    }
    f32x4 ahh0, ahh1, alh0, alh1, ahl0, ahl1;
    const char* base = &lds[cur][0];
    #pragma unroll
    for (int ks = 0; ks < 6; ++ks) {
      const int ro = col * PITCHB + ((ks*64 + kb*16) ^ swz);
      bf16x8 bh = *(const bf16x8*)(base + ro);
      bf16x8 bl = *(const bf16x8*)(base + 6144 + ro);
      if (ks == 0) {
        ahh0 = __builtin_amdgcn_mfma_f32_16x16x32_bf16(ahi[0][0], bh, z4, 0, 0, 0);
        ahh1 = __builtin_amdgcn_mfma_f32_16x16x32_bf16(ahi[1][0], bh, z4, 0, 0, 0);
        alh0 = __builtin_amdgcn_mfma_f32_16x16x32_bf16(alo[0][0], bh, z4, 0, 0, 0);
        alh1 = __builtin_amdgcn_mfma_f32_16x16x32_bf16(alo[1][0], bh, z4, 0, 0, 0);
        ahl0 = __builtin_amdgcn_mfma_f32_16x16x32_bf16(ahi[0][0], bl, z4, 0, 0, 0);
        ahl1 = __builtin_amdgcn_mfma_f32_16x16x32_bf16(ahi[1][0], bl, z4, 0, 0, 0);
      } else {
        ahh0 = __builtin_amdgcn_mfma_f32_16x16x32_bf16(ahi[0][ks], bh, ahh0, 0, 0, 0);
        ahh1 = __builtin_amdgcn_mfma_f32_16x16x32_bf16(ahi[1][ks], bh, ahh1, 0, 0, 0);
        alh0 = __builtin_amdgcn_mfma_f32_16x16x32_bf16(alo[0][ks], bh, alh0, 0, 0, 0);
        alh1 = __builtin_amdgcn_mfma_f32_16x16x32_bf16(alo[1][ks], bh, alh1, 0, 0, 0);
        ahl0 = __builtin_amdgcn_mfma_f32_16x16x32_bf16(ahi[0][ks], bl, ahl0, 0, 0, 0);
        ahl1 = __builtin_amdgcn_mfma_f32_16x16x32_bf16(ahi[1][ks], bl, ahl1, 0, 0, 0);
      }
    }
    const float cbase = (float)(c0g + t*16 + col);
    #pragma unroll
    for (int mf = 0; mf < 2; ++mf)
      #pragma unroll
      for (int e = 0; e < 4; ++e) {
        const int s = mf*4 + e;
        float c = mf ? (ahh1[e] + alh1[e] + ahl1[e]) : (ahh0[e] + alh0[e] + ahl0[e]);
        sacc[s] += __expf(fmaf(SSC, c, -SSC));
        bool gt = c > v1[s];
        v2[s] = gt ? v1[s] : fmaxf(v2[s], c);
        i1[s] = gt ? cbase : i1[s];
        v1[s] = gt ? c : v1[s];
      }
    __syncthreads();
  }

  // reduce across the 16 class-columns (lane bits 0-3)
  #pragma unroll
  for (int m = 1; m < 16; m <<= 1) {
    #pragma unroll
    for (int s = 0; s < 8; ++s) {
      sacc[s] += __shfl_xor(sacc[s], m);
      float ov1 = __shfl_xor(v1[s], m);
      float ov2 = __shfl_xor(v2[s], m);
      float oi  = __shfl_xor(i1[s], m);
      bool gt = ov1 > v1[s];
      v2[s] = fmaxf(v2[s], gt ? fmaxf(v1[s], ov2) : ov1);
      i1[s] = gt ? oi : i1[s];
      v1[s] = gt ? ov1 : v1[s];
    }
  }
  if (col == 0) {
    #pragma unroll
    for (int s = 0; s < 8; ++s) {
      int row = r0w + (s >> 2) * 16 + kb * 4 + (s & 3);
      size_t o = (size_t)row * NCG + blockIdx.y;
      s_part[o] = sacc[s]; b1p[o] = v1[s]; b2p[o] = v2[s]; bip[o] = i1[s];
    }
  }
}

// ---------- merge: exact label logit, loss, flag ambiguous argmax rows ----------
__global__ __launch_bounds__(256) void arc_merge(
    const float* __restrict__ x, const float* __restrict__ W,
    const int* __restrict__ labels, const float* __restrict__ s_part,
    const float* __restrict__ b1p, const float* __restrict__ b2p,
    const float* __restrict__ bip, float* __restrict__ loss_row,
    float* __restrict__ corr_row, int* __restrict__ nflag,
    int* __restrict__ list, unsigned long long* __restrict__ keybuf) {
  const int r = blockIdx.x * 4 + (threadIdx.x >> 6);
  const int lane = threadIdx.x & 63;
  const int y = labels[r];
  const float* xr = x + (size_t)r * KDIM;
  const float* wy = W + (size_t)y * KDIM;
  float a0 = xr[lane], a1 = xr[lane+64], a2 = xr[lane+128];
  float b0 = wy[lane], b1 = wy[lane+64], b2 = wy[lane+128];
  float ssx = a0*a0 + a1*a1 + a2*a2;
  float ssw = b0*b0 + b1*b1 + b2*b2;
  float d   = a0*b0 + a1*b1 + a2*b2;
  #pragma unroll
  for (int m = 1; m < 64; m <<= 1) {
    ssx += __shfl_xor(ssx, m); ssw += __shfl_xor(ssw, m); d += __shfl_xor(d, m);
  }
  if (lane == 0) {
    const float rnx = 1.0f / fmaxf(sqrtf(ssx), 1e-12f);
    const float rnwv = 1.0f / fmaxf(sqrtf(ssw), 1e-12f);
    const float cy = d * rnx * rnwv;
    float s = 0.f, v1 = -3.f, v2 = -3.f, i1 = 0.f;
    #pragma unroll
    for (int g = 0; g < 8; ++g) {
      size_t o = (size_t)r * NCG + g;
      s += s_part[o];
      float pv1 = b1p[o], pv2 = b2p[o], pi = bip[o];
      bool gt = pv1 > v1;
      v2 = fmaxf(v2, gt ? fmaxf(v1, pv2) : pv1);
      i1 = gt ? pi : i1;
      v1 = gt ? pv1 : v1;
    }
    const float sine = sqrtf(fmaxf(0.f, 1.f - cy*cy));
    const float cp = (cy > THRV) ? (cy*COSM - sine*SINM) : (cy - MMV);
    const float zy = SSC * cp, zy0 = SSC * cy;
    const float s2 = s - __expf(zy0 - SSC) + __expf(zy - SSC);
    loss_row[r] = SSC + logf(s2) - zy;
    float corr = ((int)i1 == y) ? 1.f : 0.f;
    if (v1 - v2 < FLAG_GAP) {
      int sl = atomicAdd(nflag, 1);
      list[sl] = r;
      keybuf[r] = 0ull;
      corr = -1.f;
    }
    corr_row[r] = corr;
  }
}

// ---------- fixup: exact fp32 argmax for flagged rows (order-independent) ----------
__global__ __launch_bounds__(256) void arc_fixup(
    const float* __restrict__ x, const float* __restrict__ W,
    const float* __restrict__ rnw, const int* __restrict__ nflag,
    const int* __restrict__ list, unsigned long long* __restrict__ keybuf) {
  __shared__ float xs[4][KDIM];
  __shared__ unsigned long long kred[256];
  const int tid = threadIdx.x;
  const int nf = *nflag;
  const int nit = ((nf + 3) >> 2) * 6;
  for (int it = blockIdx.x; it < nit; it += gridDim.x) {
    const int fc = it / 6, win = it % 6;
    __syncthreads();
    for (int e = tid; e < 4 * KDIM; e += 256) {
      int i = e / KDIM, k = e % KDIM;
      int fi = fc * 4 + i;
      int rr = list[fi < nf ? fi : 0];
      xs[i][k] = x[(size_t)rr * KDIM + k];
    }
    __syncthreads();
    const int cb = win * 1024;
    unsigned long long kk[4] = {0ull, 0ull, 0ull, 0ull};
    #pragma unroll 1
    for (int j = 0; j < 4; ++j) {
      int c = cb + tid + j * 256;
      if (c < NCLS) {
        const float4* wc = (const float4*)(W + (size_t)c * KDIM);
        float d0 = 0.f, d1 = 0.f, d2 = 0.f, d3 = 0.f;
        #pragma unroll 8
        for (int k4 = 0; k4 < 48; ++k4) {
          float4 wv = wc[k4];
          float4 x0 = *(const float4*)&xs[0][k4*4];
          float4 x1 = *(const float4*)&xs[1][k4*4];
          float4 x2 = *(const float4*)&xs[2][k4*4];
          float4 x3 = *(const float4*)&xs[3][k4*4];
          d0 = fmaf(wv.x,x0.x,fmaf(wv.y,x0.y,fmaf(wv.z,x0.z,fmaf(wv.w,x0.w,d0))));
          d1 = fmaf(wv.x,x1.x,fmaf(wv.y,x1.y,fmaf(wv.z,x1.z,fmaf(wv.w,x1.w,d1))));
          d2 = fmaf(wv.x,x2.x,fmaf(wv.y,x2.y,fmaf(wv.z,x2.z,fmaf(wv.w,x2.w,d2))));
          d3 = fmaf(wv.x,x3.x,fmaf(wv.y,x3.y,fmaf(wv.z,x3.z,fmaf(wv.w,x3.w,d3))));
        }
        const float rw = rnw[c];
        const float dd0 = d0*rw, dd1 = d1*rw, dd2 = d2*rw, dd3 = d3*rw;
        const float dv[4] = {dd0, dd1, dd2, dd3};
        #pragma unroll
        for (int i = 0; i < 4; ++i) {
          float v = dv[i];
          unsigned int ub = __float_as_uint(v);
          unsigned int k32 = (v < 0.f) ? ~ub : (ub | 0x80000000u);
          unsigned long long key = ((unsigned long long)k32 << 32) | (unsigned int)(8191 - c);
          kk[i] = kk[i] > key ? kk[i] : key;
        }
      }
    }
    #pragma unroll 1
    for (int i = 0; i < 4; ++i) {
      kred[tid] = kk[i];
      __syncthreads();
      for (int st = 128; st > 0; st >>= 1) {
        if (tid < st) kred[tid] = kred[tid] > kred[tid + st] ? kred[tid] : kred[tid + st];
        __syncthreads();
      }
      if (tid == 0) {
        int fi = fc * 4 + i;
        if (fi < nf) atomicMax(&keybuf[list[fi]], kred[0]);
      }
      __syncthreads();
    }
  }
}

// ---------- final reduction ----------
__global__ __launch_bounds__(256) void arc_final(
    const float* __restrict__ loss_row, const float* __restrict__ corr_row,
    const int* __restrict__ labels, const unsigned long long* __restrict__ keybuf,
    float* __restrict__ out) {
  __shared__ double redl[256];
  __shared__ double redc[256];
  const int t = threadIdx.x;
  double ls = 0.0, cs = 0.0;
  for (int i = t; i < NROWS; i += 256) {
    ls += (double)loss_row[i];
    float c = corr_row[i];
    if (c < 0.f) {
      int cls = 8191 - (int)(keybuf[i] & 0xffffffffull);
      c = (cls == labels[i]) ? 1.f : 0.f;
    }
    cs += (double)c;
  }
  redl[t] = ls; redc[t] = cs;
  __syncthreads();
  for (int st = 128; st > 0; st >>= 1) {
    if (t < st) { redl[t] += redl[t + st]; redc[t] += redc[t + st]; }
    __syncthreads();
  }
  if (t == 0) {
    out[0] = (float)(redl[0] / (double)NROWS);
    out[1] = (float)redc[0];
  }
}

extern "C" void kernel_launch(void* const* d_in, const int* in_sizes, int n_in,
                              void* d_out, int out_size, void* d_ws, size_t ws_size,
                              hipStream_t stream) {
  const float* x = (const float*)d_in[0];
  const int* labels = (const int*)d_in[1];
  const float* W = (const float*)d_in[2];
  float* out = (float*)d_out;
  char* ws = (char*)d_ws;

  size_t off = 0;
  unsigned short* Whi = (unsigned short*)(ws + off); off += (size_t)NCLSP * KDIM * 2;
  unsigned short* Wlo = (unsigned short*)(ws + off); off += (size_t)NCLSP * KDIM * 2;
  unsigned short* Xhi = (unsigned short*)(ws + off); off += (size_t)NROWS * KDIM * 2;
  unsigned short* Xlo = (unsigned short*)(ws + off); off += (size_t)NROWS * KDIM * 2;
  float* rnw = (float*)(ws + off);          off += (size_t)NCLSP * 4 + 128;
  float* s_part = (float*)(ws + off);       off += (size_t)NROWS * NCG * 4;
  float* b1p = (float*)(ws + off);          off += (size_t)NROWS * NCG * 4;
  float* b2p = (float*)(ws + off);          off += (size_t)NROWS * NCG * 4;
  float* bip = (float*)(ws + off);          off += (size_t)NROWS * NCG * 4;
  float* loss_row = (float*)(ws + off);     off += (size_t)NROWS * 4;
  float* corr_row = (float*)(ws + off);     off += (size_t)NROWS * 4;
  unsigned long long* keybuf = (unsigned long long*)(ws + off); off += (size_t)NROWS * 8;
  int* list = (int*)(ws + off);             off += (size_t)NROWS * 4;
  int* nflag = (int*)(ws + off);            off += 64;

  hipLaunchKernelGGL(wprep, dim3(NCLSP / 4), dim3(256), 0, stream, W, Whi, Wlo, rnw);
  hipLaunchKernelGGL(xprep, dim3(NROWS / 4), dim3(256), 0, stream, x, Xhi, Xlo, nflag);
  hipLaunchKernelGGL(arc_main, dim3(64, 8), dim3(256), 0, stream, Xhi, Xlo, Whi, Wlo,
                     s_part, b1p, b2p, bip);
  hipLaunchKernelGGL(arc_merge, dim3(NROWS / 4), dim3(256), 0, stream, x, W, labels,
                     s_part, b1p, b2p, bip, loss_row, corr_row, nflag, list, keybuf);
  hipLaunchKernelGGL(arc_fixup, dim3(512), dim3(256), 0, stream, x, W, rnw, nflag,
                     list, keybuf);
  hipLaunchKernelGGL(arc_final, dim3(1), dim3(256), 0, stream, loss_row, corr_row,
                     labels, keybuf, out);
}